// Round 1
// baseline (105.033 us; speedup 1.0000x reference)
//
#include <hip/hip_runtime.h>

typedef float   f32x16 __attribute__((ext_vector_type(16)));
typedef _Float16 f16x8 __attribute__((ext_vector_type(8)));

#define NWAVES 4
#define TPW 4
#define TILES_PER_BLOCK (NWAVES * TPW)

// Per edge: raw = concat(zi[src] (64), zj[dst] (64));
// hid = relu(raw @ W1^T + b1) [128]; score = sigmoid(hid . W3 + b3).
// neg_score == pos_score (source bug: both scored from raw_pos).
__global__ __launch_bounds__(256) void graphlp_mfma(
    const float* __restrict__ zi, const float* __restrict__ zj,
    const float* __restrict__ W1, const float* __restrict__ b1,
    const float* __restrict__ W3, const float* __restrict__ b3p,
    const int* __restrict__ psrc, const int* __restrict__ pdst,
    float* __restrict__ out, const int nEdges, const int nTiles)
{
    // W1 as f16, swizzled: byte = row*256 + ((k*2) ^ ((row&7)<<4)); 32 KiB
    __shared__ uint4 w1s[2048];
    char* lds = reinterpret_cast<char*>(w1s);
    const int tid = threadIdx.x;

    #pragma unroll
    for (int i = 0; i < 8; ++i) {
        const int ch  = tid + i * 256;   // 2048 chunks of 8 f32
        const int row = ch >> 4;         // 0..127 (hidden unit n)
        const int kg  = ch & 15;         // 8-wide k group
        const float* s = W1 + row * 128 + kg * 8;
        const float4 a0 = *reinterpret_cast<const float4*>(s);
        const float4 a1 = *reinterpret_cast<const float4*>(s + 4);
        f16x8 v;
        v[0] = (_Float16)a0.x; v[1] = (_Float16)a0.y;
        v[2] = (_Float16)a0.z; v[3] = (_Float16)a0.w;
        v[4] = (_Float16)a1.x; v[5] = (_Float16)a1.y;
        v[6] = (_Float16)a1.z; v[7] = (_Float16)a1.w;
        const int off = row * 256 + ((kg * 16) ^ ((row & 7) << 4));
        *reinterpret_cast<f16x8*>(lds + off) = v;
    }
    __syncthreads();

    const int lane = tid & 63;
    const int wav  = tid >> 6;
    const int lr   = lane & 31;   // edge-row / n-col within 32
    const int lq   = lane >> 5;   // k-half selector

    float b1v[4], w3v[4];
    #pragma unroll
    for (int nb = 0; nb < 4; ++nb) {
        b1v[nb] = b1[nb * 32 + lr];
        w3v[nb] = W3[nb * 32 + lr];
    }
    const float b3 = b3p[0];

    for (int t = 0; t < TPW; ++t) {
        const int g = blockIdx.x * TILES_PER_BLOCK + t * NWAVES + wav;
        if (g >= nTiles) break;          // wave-uniform
        const int ebase = g * 32;
        int e = ebase + lr;
        if (e >= nEdges) e = nEdges - 1; // clamp (tail tile)
        const int si = psrc[e];
        const int di = pdst[e];
        const float* __restrict__ sp = zi + (size_t)si * 64;
        const float* __restrict__ dp = zj + (size_t)di * 64;

        // A fragments: lane holds raw[lr][kk*16 + lq*8 .. +8)
        f16x8 afrag[8];
        #pragma unroll
        for (int kk = 0; kk < 8; ++kk) {
            const int kb = kk * 16 + lq * 8;                 // 0..120, step 8
            const float* p = (kk < 4) ? (sp + kb) : (dp + kb - 64);
            const float4 a0 = *reinterpret_cast<const float4*>(p);
            const float4 a1 = *reinterpret_cast<const float4*>(p + 4);
            f16x8 v;
            v[0] = (_Float16)a0.x; v[1] = (_Float16)a0.y;
            v[2] = (_Float16)a0.z; v[3] = (_Float16)a0.w;
            v[4] = (_Float16)a1.x; v[5] = (_Float16)a1.y;
            v[6] = (_Float16)a1.z; v[7] = (_Float16)a1.w;
            afrag[kk] = v;
        }

        f32x16 acc[4];
        #pragma unroll
        for (int nb = 0; nb < 4; ++nb) {
            #pragma unroll
            for (int r = 0; r < 16; ++r) acc[nb][r] = 0.0f;
        }

        #pragma unroll
        for (int kk = 0; kk < 8; ++kk) {
            #pragma unroll
            for (int nb = 0; nb < 4; ++nb) {
                const int n = nb * 32 + lr;                  // W1 row
                const int off = n * 256 + (((kk * 32) + (lq * 16)) ^ ((n & 7) << 4));
                const f16x8 bfrag = *reinterpret_cast<const f16x8*>(lds + off);
                acc[nb] = __builtin_amdgcn_mfma_f32_32x32x16_f16(
                              afrag[kk], bfrag, acc[nb], 0, 0, 0);
            }
        }

        // Epilogue: hid = relu(acc + b1); partial dot with W3 per lane
        float pr[16];
        #pragma unroll
        for (int r = 0; r < 16; ++r) {
            float ssum = 0.0f;
            #pragma unroll
            for (int nb = 0; nb < 4; ++nb) {
                float h = acc[nb][r] + b1v[nb];
                h = fmaxf(h, 0.0f);
                ssum = fmaf(h, w3v[nb], ssum);
            }
            pr[r] = ssum;
        }
        // reduce over the 32 n-lanes (butterfly; stays inside 32-group)
        #pragma unroll
        for (int m = 1; m <= 16; m <<= 1) {
            #pragma unroll
            for (int r = 0; r < 16; ++r) pr[r] += __shfl_xor(pr[r], m);
        }
        if (lr == 0) {
            // C/D layout: row m = (r&3) + 8*(r>>2) + 4*lq
            #pragma unroll
            for (int r = 0; r < 16; ++r) {
                const int mloc = (r & 3) + 8 * (r >> 2) + 4 * lq;
                const int eo = ebase + mloc;
                if (eo < nEdges) {
                    const float logit = pr[r] + b3;
                    const float score = 1.0f / (1.0f + __expf(-logit));
                    out[eo] = score;            // pos_score
                    out[nEdges + eo] = score;   // neg_score (== pos)
                }
            }
        }
    }
}

extern "C" void kernel_launch(void* const* d_in, const int* in_sizes, int n_in,
                              void* d_out, int out_size, void* d_ws, size_t ws_size,
                              hipStream_t stream)
{
    const float* zi = (const float*)d_in[0];
    const float* zj = (const float*)d_in[1];
    // d_in[2] = zn  (unused: neg path is dead code in the reference)
    const float* W1 = (const float*)d_in[3];
    const float* b1 = (const float*)d_in[4];
    const float* W3 = (const float*)d_in[5];
    const float* b3 = (const float*)d_in[6];
    const int* psrc = (const int*)d_in[7];
    const int* pdst = (const int*)d_in[8];
    // d_in[9], d_in[10] = neg_src/neg_dst (unused)
    float* out = (float*)d_out;

    const int nEdges = in_sizes[7];
    const int nTiles = (nEdges + 31) / 32;
    const int nBlocks = (nTiles + TILES_PER_BLOCK - 1) / TILES_PER_BLOCK;
    hipLaunchKernelGGL(graphlp_mfma, dim3(nBlocks), dim3(256), 0, stream,
                       zi, zj, W1, b1, W3, b3, psrc, pdst, out, nEdges, nTiles);
}